// Round 4
// baseline (4837.974 us; speedup 1.0000x reference)
//
#include <hip/hip_runtime.h>
#include <hip/hip_cooperative_groups.h>
#include <math.h>

namespace cg = cooperative_groups;

// Problem constants
#define VV 32000   // vocab
#define SS 512     // states
#define BB 64      // batch
#define TT 256     // maxlen
#define NS 128     // column groups of 4 (512/4)

// Single persistent cooperative kernel.
// Grid: 256 blocks x 256 threads (1 block/CU).
// Main-loop decomposition (as round 3): chain c = blk&1, column group g = blk>>1
// (4 output columns), wave h = j-quarter of K (LDS reduce), lane = batch b.
__global__ __launch_bounds__(256) void k_hmm(
    const int* __restrict__ sent, const float* __restrict__ masks,
    const float* __restrict__ iw, const float* __restrict__ trans,
    const float* __restrict__ begin,
    float* __restrict__ P, float* __restrict__ colLSE,
    float* __restrict__ psum, float* __restrict__ sb,
    float* __restrict__ q0vec, float* __restrict__ wring,
    float* __restrict__ dotpart, float* __restrict__ out) {
  cg::grid_group grid = cg::this_grid();
  const int blk = blockIdx.x;
  const int lane = threadIdx.x & 63;
  const int h = __builtin_amdgcn_readfirstlane(threadIdx.x >> 6);  // wave 0..3

  __shared__ float4 red[4][64];   // GEMM j-split partials / final reduce
  __shared__ float4 redC[4];      // colsum cross-wave reduce

  // ---------------- Phase A: colsum partials, begin softmax, zero out ----
  if (blk == 255) {
    if (threadIdx.x == 0) out[0] = 0.f;
    if (h == 0) {
      // sb = softmax(begin), one wave, 8 elems/lane
      float xs[8];
      float m = -1e30f;
      #pragma unroll
      for (int cc = 0; cc < 8; ++cc) {
        xs[cc] = begin[cc * 64 + lane];
        m = fmaxf(m, xs[cc]);
      }
      #pragma unroll
      for (int o = 32; o; o >>= 1) m = fmaxf(m, __shfl_xor(m, o));
      float s = 0.f;
      #pragma unroll
      for (int cc = 0; cc < 8; ++cc) s += __expf(xs[cc] - m);
      #pragma unroll
      for (int o = 32; o; o >>= 1) s += __shfl_xor(s, o);
      const float inv = 1.f / s;
      #pragma unroll
      for (int cc = 0; cc < 8; ++cc) sb[cc * 64 + lane] = __expf(xs[cc] - m) * inv;
    }
  }
  {
    // column sums of exp(iw): block handles 125 vocab rows. Inputs are
    // U(-0.5,0.5) so exp() in (0.6,1.65) — no max-subtraction needed.
    const int cg4 = threadIdx.x & 127;  // float4 column group
    const int rh = threadIdx.x >> 7;    // row parity
    const int r0 = blk * 125;
    const float4* iw4 = (const float4*)iw;  // [32000][128]
    float4 s = make_float4(0.f, 0.f, 0.f, 0.f);
    for (int r = rh; r < 125; r += 2) {
      float4 x = iw4[(size_t)(r0 + r) * 128 + cg4];
      s.x += __expf(x.x); s.y += __expf(x.y);
      s.z += __expf(x.z); s.w += __expf(x.w);
    }
    ((float4*)psum)[(size_t)(blk * 2 + rh) * 128 + cg4] = s;
  }
  grid.sync();

  // ---------------- Phase B: P softmax rows | colLSE reduce ---------------
  if (blk < 128) {
    // P[i][j] = softmax(trans[i,:]) (row per wave), q0vec[i] = P[i,:]. sb
    const int i = blk * 4 + h;
    const float* rp = trans + (size_t)i * SS;
    float xs[8];
    float m = -1e30f;
    #pragma unroll
    for (int cc = 0; cc < 8; ++cc) {
      xs[cc] = rp[cc * 64 + lane];
      m = fmaxf(m, xs[cc]);
    }
    #pragma unroll
    for (int o = 32; o; o >>= 1) m = fmaxf(m, __shfl_xor(m, o));
    float s = 0.f;
    #pragma unroll
    for (int cc = 0; cc < 8; ++cc) s += __expf(xs[cc] - m);
    #pragma unroll
    for (int o = 32; o; o >>= 1) s += __shfl_xor(s, o);
    const float lse = m + __logf(s);
    float qa = 0.f;
    #pragma unroll
    for (int cc = 0; cc < 8; ++cc) {
      float p = __expf(xs[cc] - lse);
      P[(size_t)i * SS + cc * 64 + lane] = p;
      qa += p * sb[cc * 64 + lane];
    }
    #pragma unroll
    for (int o = 32; o; o >>= 1) qa += __shfl_xor(qa, o);
    if (lane == 0) q0vec[i] = qa;
  } else {
    // colLSE for 4 columns c0..c0+3: sum 512 partials, log
    const int c0 = (blk - 128) << 2;
    const float4* ps0 = (const float4*)(psum + (size_t)threadIdx.x * SS + c0);
    const float4* ps1 = (const float4*)(psum + (size_t)(threadIdx.x + 256) * SS + c0);
    float4 a = ps0[0], b = ps1[0];
    float4 s = make_float4(a.x + b.x, a.y + b.y, a.z + b.z, a.w + b.w);
    #pragma unroll
    for (int o = 32; o; o >>= 1) {
      s.x += __shfl_xor(s.x, o);
      s.y += __shfl_xor(s.y, o);
      s.z += __shfl_xor(s.z, o);
      s.w += __shfl_xor(s.w, o);
    }
    if (lane == 0) redC[h] = s;
    __syncthreads();
    if (threadIdx.x == 0) {
      float4 t0 = redC[0], t1 = redC[1], t2 = redC[2], t3 = redC[3];
      colLSE[c0 + 0] = __logf((t0.x + t1.x) + (t2.x + t3.x));
      colLSE[c0 + 1] = __logf((t0.y + t1.y) + (t2.y + t3.y));
      colLSE[c0 + 2] = __logf((t0.z + t1.z) + (t2.z + t3.z));
      colLSE[c0 + 3] = __logf((t0.w + t1.w) + (t2.w + t3.w));
    }
  }
  grid.sync();

  // ---------------- Phase C: 129 supersteps ------------------------------
  const int c = blk & 1;
  const int g = blk >> 1;   // 0..127
  const int i0 = g << 2;

  for (int t0 = 0; t0 <= 256; t0 += 2) {
    const bool active = !(c == 1 && t0 == 256);
    float* wA = wring + (size_t)((t0 + 2) & 3) * (BB * SS); // slot (t0-2)%4
    float* wB = wring + (size_t)((t0 + 3) & 3) * (BB * SS); // slot (t0-1)%4
    float* wC = wring + (size_t)(t0 & 3) * (BB * SS);       // slot t0%4
    float* wD = wring + (size_t)((t0 + 1) & 3) * (BB * SS); // slot (t0+1)%4

    const int tw = t0 + c;
    const int td = tw - 1;
    const bool doW = active && (h == 0) && (tw <= 254);
    const bool doD = active && (h == 1) && (td >= 0);

    // Prefetch scattered iw gathers so latency overlaps the GEMM.
    float4 ivW = make_float4(0.f, 0.f, 0.f, 0.f);
    float4 ivD = make_float4(0.f, 0.f, 0.f, 0.f);
    if (doW) {
      const int row = sent[lane * TT + tw];
      ivW = *(const float4*)(iw + (size_t)row * SS + i0);
    }
    if (doD) {
      const int row = sent[lane * TT + td];
      ivD = *(const float4*)(iw + (size_t)row * SS + i0);
    }

    float a0 = 0.f, a1 = 0.f, a2 = 0.f, a3 = 0.f;
    if (active) {
      if (t0 == 0) {
        if (h == 0) {
          a0 = q0vec[i0 + 0]; a1 = q0vec[i0 + 1];
          a2 = q0vec[i0 + 2]; a3 = q0vec[i0 + 3];
        }
      } else {
        const float4* wv = (const float4*)(c ? wB : wA) + (size_t)h * 32 * 64;
        const float4* P0 = (const float4*)(P + (size_t)(i0 + 0) * SS) + h * 32;
        const float4* P1 = (const float4*)(P + (size_t)(i0 + 1) * SS) + h * 32;
        const float4* P2 = (const float4*)(P + (size_t)(i0 + 2) * SS) + h * 32;
        const float4* P3 = (const float4*)(P + (size_t)(i0 + 3) * SS) + h * 32;
        #pragma unroll 4
        for (int j4 = 0; j4 < 32; ++j4) {
          const float4 w4 = wv[j4 * 64 + lane];
          const float4 p0 = P0[j4];
          const float4 p1 = P1[j4];
          const float4 p2 = P2[j4];
          const float4 p3 = P3[j4];
          a0 += w4.x * p0.x + w4.y * p0.y + w4.z * p0.z + w4.w * p0.w;
          a1 += w4.x * p1.x + w4.y * p1.y + w4.z * p1.z + w4.w * p1.w;
          a2 += w4.x * p2.x + w4.y * p2.y + w4.z * p2.z + w4.w * p2.w;
          a3 += w4.x * p3.x + w4.y * p3.y + w4.z * p3.z + w4.w * p3.w;
        }
      }
    }

    red[h][lane] = make_float4(a0, a1, a2, a3);
    __syncthreads();

    if (h < 2 && active) {
      const float4 r0 = red[0][lane], r1 = red[1][lane];
      const float4 r2 = red[2][lane], r3 = red[3][lane];
      const float s0 = (r0.x + r1.x) + (r2.x + r3.x);
      const float s1 = (r0.y + r1.y) + (r2.y + r3.y);
      const float s2 = (r0.z + r1.z) + (r2.z + r3.z);
      const float s3 = (r0.w + r1.w) + (r2.w + r3.w);

      const float4 cl = *(const float4*)(colLSE + i0);

      if (doW) {
        float w0 = s0 * __expf(ivW.x - cl.x);
        float w1 = s1 * __expf(ivW.y - cl.y);
        float w2 = s2 * __expf(ivW.z - cl.z);
        float w3 = s3 * __expf(ivW.w - cl.w);
        float c0 = w0, c1 = w1, c2 = w2, c3 = w3;
        #pragma unroll
        for (int o = 32; o; o >>= 1) {
          c0 += __shfl_xor(c0, o);
          c1 += __shfl_xor(c1, o);
          c2 += __shfl_xor(c2, o);
          c3 += __shfl_xor(c3, o);
        }
        float* wdst = c ? wD : wC;
        float4 wo;
        wo.x = w0 / c0; wo.y = w1 / c1; wo.z = w2 / c2; wo.w = w3 / c3;
        ((float4*)wdst)[g * 64 + lane] = wo;
      }

      if (doD) {
        const float dp = s0 * __expf(ivD.x - cl.x)
                       + s1 * __expf(ivD.y - cl.y)
                       + s2 * __expf(ivD.z - cl.z)
                       + s3 * __expf(ivD.w - cl.w);
        dotpart[((size_t)td * NS + g) * BB + lane] = dp;
      }
    }

    grid.sync();
  }

  // ---------------- Phase D: final reduction (t = blk) -------------------
  {
    const int t = blk;
    const int b = lane;
    float sum = 0.f;
    for (int s = h; s < NS; s += 4)
      sum += dotpart[((size_t)t * NS + s) * BB + b];
    red[h][b].x = sum;
    __syncthreads();
    if (h == 0) {
      float tot = (red[0][b].x + red[1][b].x) + (red[2][b].x + red[3][b].x);
      float v = __logf(tot) * masks[b * TT + t];
      #pragma unroll
      for (int o = 32; o; o >>= 1) v += __shfl_xor(v, o);
      if (b == 0) atomicAdd(out, v);
    }
  }
}

extern "C" void kernel_launch(void* const* d_in, const int* in_sizes, int n_in,
                              void* d_out, int out_size, void* d_ws, size_t ws_size,
                              hipStream_t stream) {
  const int* sent = (const int*)d_in[0];      // [64][256] int32
  const float* masks = (const float*)d_in[1]; // [64][256]
  const float* iw = (const float*)d_in[2];    // [32000][512]
  const float* trans = (const float*)d_in[3]; // [512][512]
  const float* begin = (const float*)d_in[4]; // [512]
  float* out = (float*)d_out;
  float* ws = (float*)d_ws;

  // workspace carve (floats)
  float* P = ws;                          // 262144
  float* colLSE = P + 262144;             // 512
  float* psum = colLSE + 512;             // 512*512 = 262144
  float* sb = psum + 262144;              // 512
  float* q0vec = sb + 512;                // 512
  float* wring = q0vec + 512;             // 4 * 512*64 = 131072
  float* dotpart = wring + 4 * (BB * SS); // 256*128*64 = 2097152
  // total ~2.75M floats ~11 MB

  void* args[] = {(void*)&sent, (void*)&masks, (void*)&iw, (void*)&trans,
                  (void*)&begin, (void*)&P, (void*)&colLSE, (void*)&psum,
                  (void*)&sb, (void*)&q0vec, (void*)&wring, (void*)&dotpart,
                  (void*)&out};
  hipLaunchCooperativeKernel((void*)k_hmm, dim3(256), dim3(256), args, 0, stream);
}

// Round 5
// 2626.720 us; speedup vs baseline: 1.8418x; 1.8418x over previous
//
#include <hip/hip_runtime.h>
#include <math.h>

// Problem constants
#define VV 32000   // vocab
#define SS 512     // states
#define BB 64      // batch
#define TT 256     // maxlen
#define NBLK 128   // persistent blocks
#define AG __HIP_MEMORY_SCOPE_AGENT

// Zero the barrier slots + output before the persistent kernel starts.
__global__ void k_init(float* __restrict__ out, unsigned* __restrict__ bar) {
  if (threadIdx.x == 0) out[0] = 0.f;
  bar[threadIdx.x] = 0u;  // 256 slots
}

// Sense-reversing grid barrier on agent-scope (LLC-coherent) atomics.
// cg::grid.sync() measured ~35us/sync (system-scope + long s_sleep backoff);
// this is the light version: relaxed arrive/spin + explicit agent fences.
__device__ __forceinline__ void gbar(unsigned* cnt, unsigned* gen, unsigned n) {
  __syncthreads();
  if (threadIdx.x == 0) {
    __builtin_amdgcn_fence(__ATOMIC_RELEASE, "agent");
    unsigned g = __hip_atomic_load(gen, __ATOMIC_RELAXED, AG);
    unsigned a = __hip_atomic_fetch_add(cnt, 1u, __ATOMIC_RELAXED, AG);
    if (a == n - 1u) {
      __builtin_amdgcn_fence(__ATOMIC_ACQUIRE, "agent");
      __hip_atomic_store(cnt, 0u, __ATOMIC_RELAXED, AG);
      __hip_atomic_store(gen, g + 1u, __ATOMIC_RELEASE, AG);
    } else {
      while (__hip_atomic_load(gen, __ATOMIC_RELAXED, AG) == g)
        __builtin_amdgcn_s_sleep(2);
      __builtin_amdgcn_fence(__ATOMIC_ACQUIRE, "agent");
    }
  }
  __syncthreads();
}

// Persistent kernel: 128 blocks x 256 threads (co-resident via cooperative
// launch; barriers are custom). Phase C decomposition: chain c = blk&1,
// group g = blk>>1 (8 output columns), wave h = j-quarter of K, lane = batch.
__global__ __launch_bounds__(256) void k_hmm(
    const int* __restrict__ sent, const float* __restrict__ masks,
    const float* __restrict__ iw, const float* __restrict__ trans,
    const float* __restrict__ begin,
    float* __restrict__ P, float* __restrict__ colLSE,
    float* __restrict__ psum, float* __restrict__ sb,
    float* __restrict__ q0vec, float* __restrict__ wring,
    float* __restrict__ dotpart, float* __restrict__ out,
    unsigned* __restrict__ bar) {
  const int blk = blockIdx.x;
  const int tid = threadIdx.x;
  const int lane = tid & 63;
  const int h = __builtin_amdgcn_readfirstlane(tid >> 6);  // wave 0..3

  unsigned* cntC = bar + (blk & 1) * 64;       // per-chain barrier (64 blocks)
  unsigned* genC = cntC + 32;
  unsigned* cntF = bar + 128;                  // full barrier (128 blocks)
  unsigned* genF = bar + 160;

  __shared__ float4 red[4][64][2];  // j-split partials (8 cols = 2 float4)
  __shared__ float4 redC[4];

  // ---- Phase A: colsum partials (250 vocab rows/block); sb on block 0 ----
  {
    const int cg4 = tid & 127;  // float4 column group
    const int rh = tid >> 7;    // row parity
    const int r0 = blk * 250;
    const float4* iw4 = (const float4*)iw;  // [32000][128]
    float4 s = make_float4(0.f, 0.f, 0.f, 0.f);
    for (int r = rh; r < 250; r += 2) {
      float4 x = iw4[(size_t)(r0 + r) * 128 + cg4];
      s.x += __expf(x.x); s.y += __expf(x.y);
      s.z += __expf(x.z); s.w += __expf(x.w);
    }
    ((float4*)psum)[(size_t)(blk * 2 + rh) * 128 + cg4] = s;
  }
  if (blk == 0 && h == 0) {
    float xs[8];
    float m = -1e30f;
    #pragma unroll
    for (int cc = 0; cc < 8; ++cc) {
      xs[cc] = begin[cc * 64 + lane];
      m = fmaxf(m, xs[cc]);
    }
    #pragma unroll
    for (int o = 32; o; o >>= 1) m = fmaxf(m, __shfl_xor(m, o));
    float s = 0.f;
    #pragma unroll
    for (int cc = 0; cc < 8; ++cc) s += __expf(xs[cc] - m);
    #pragma unroll
    for (int o = 32; o; o >>= 1) s += __shfl_xor(s, o);
    const float inv = 1.f / s;
    #pragma unroll
    for (int cc = 0; cc < 8; ++cc) sb[cc * 64 + lane] = __expf(xs[cc] - m) * inv;
  }
  gbar(cntF, genF, NBLK);

  // ---- Phase B: P softmax rows + q0vec; colLSE (4 cols/block) -----------
  {
    const int i = blk * 4 + h;  // 512 rows over 128 blocks x 4 waves
    const float* rp = trans + (size_t)i * SS;
    float xs[8];
    float m = -1e30f;
    #pragma unroll
    for (int cc = 0; cc < 8; ++cc) {
      xs[cc] = rp[cc * 64 + lane];
      m = fmaxf(m, xs[cc]);
    }
    #pragma unroll
    for (int o = 32; o; o >>= 1) m = fmaxf(m, __shfl_xor(m, o));
    float s = 0.f;
    #pragma unroll
    for (int cc = 0; cc < 8; ++cc) s += __expf(xs[cc] - m);
    #pragma unroll
    for (int o = 32; o; o >>= 1) s += __shfl_xor(s, o);
    const float lse = m + __logf(s);
    float qa = 0.f;
    #pragma unroll
    for (int cc = 0; cc < 8; ++cc) {
      float p = __expf(xs[cc] - lse);
      P[(size_t)i * SS + cc * 64 + lane] = p;
      qa += p * sb[cc * 64 + lane];
    }
    #pragma unroll
    for (int o = 32; o; o >>= 1) qa += __shfl_xor(qa, o);
    if (lane == 0) q0vec[i] = qa;
  }
  {
    // colLSE for 4 columns: sum the 256 partial rows, take log
    const int c0 = blk * 4;
    const float4 a = *(const float4*)(psum + (size_t)tid * SS + c0);
    float4 s = a;
    #pragma unroll
    for (int o = 32; o; o >>= 1) {
      s.x += __shfl_xor(s.x, o);
      s.y += __shfl_xor(s.y, o);
      s.z += __shfl_xor(s.z, o);
      s.w += __shfl_xor(s.w, o);
    }
    if (lane == 0) redC[h] = s;
    __syncthreads();
    if (tid == 0) {
      float4 t0 = redC[0], t1 = redC[1], t2 = redC[2], t3 = redC[3];
      float4 o4;
      o4.x = __logf((t0.x + t1.x) + (t2.x + t3.x));
      o4.y = __logf((t0.y + t1.y) + (t2.y + t3.y));
      o4.z = __logf((t0.z + t1.z) + (t2.z + t3.z));
      o4.w = __logf((t0.w + t1.w) + (t2.w + t3.w));
      *(float4*)(colLSE + c0) = o4;
    }
  }
  gbar(cntF, genF, NBLK);

  // ---- Phase C: 129 supersteps, per-chain barrier -----------------------
  const int c = blk & 1;
  const int g = blk >> 1;        // 0..63, 8 columns each
  const int i0 = g << 3;
  const int half = h & 1;        // which 4-col half this wave handles in tail
  const int g4 = g * 2 + half;   // global 4-col group 0..127
  const int ic = i0 + half * 4;

  for (int t0 = 0; t0 <= 256; t0 += 2) {
    const bool active = !(c == 1 && t0 == 256);
    float* wA = wring + (size_t)((t0 + 2) & 3) * (BB * SS);
    float* wB = wring + (size_t)((t0 + 3) & 3) * (BB * SS);
    float* wC = wring + (size_t)(t0 & 3) * (BB * SS);
    float* wD = wring + (size_t)((t0 + 1) & 3) * (BB * SS);

    const int tw = t0 + c;
    const int td = tw - 1;
    const bool doW = active && (h < 2) && (tw <= 254);   // waves 0,1: w-phase
    const bool doD = active && (h >= 2) && (td >= 0);    // waves 2,3: dot-phase

    // Prefetch the scattered iw gather (overlaps the GEMM).
    float4 iv = make_float4(0.f, 0.f, 0.f, 0.f);
    if (doW) {
      const int row = sent[lane * TT + tw];
      iv = *(const float4*)(iw + (size_t)row * SS + ic);
    }
    if (doD) {
      const int row = sent[lane * TT + td];
      iv = *(const float4*)(iw + (size_t)row * SS + ic);
    }

    float a0 = 0.f, a1 = 0.f, a2 = 0.f, a3 = 0.f;
    float a4 = 0.f, a5 = 0.f, a6 = 0.f, a7 = 0.f;
    if (active) {
      if (t0 == 0) {
        if (h == 0) {
          a0 = q0vec[i0 + 0]; a1 = q0vec[i0 + 1];
          a2 = q0vec[i0 + 2]; a3 = q0vec[i0 + 3];
          a4 = q0vec[i0 + 4]; a5 = q0vec[i0 + 5];
          a6 = q0vec[i0 + 6]; a7 = q0vec[i0 + 7];
        }
      } else {
        const float4* wv = (const float4*)(c ? wB : wA) + (size_t)h * 32 * 64;
        // P row pointers are wave-uniform -> scalar loads
        const float* P0 = P + (size_t)(i0 + 0) * SS + h * 128;
        const float* P1 = P + (size_t)(i0 + 1) * SS + h * 128;
        const float* P2 = P + (size_t)(i0 + 2) * SS + h * 128;
        const float* P3 = P + (size_t)(i0 + 3) * SS + h * 128;
        const float* P4 = P + (size_t)(i0 + 4) * SS + h * 128;
        const float* P5 = P + (size_t)(i0 + 5) * SS + h * 128;
        const float* P6 = P + (size_t)(i0 + 6) * SS + h * 128;
        const float* P7 = P + (size_t)(i0 + 7) * SS + h * 128;
        #pragma unroll 8
        for (int j4 = 0; j4 < 32; ++j4) {
          const float4 w4 = wv[(size_t)j4 * 64 + lane];
          const float4 p0 = *(const float4*)(P0 + j4 * 4);
          const float4 p1 = *(const float4*)(P1 + j4 * 4);
          const float4 p2 = *(const float4*)(P2 + j4 * 4);
          const float4 p3 = *(const float4*)(P3 + j4 * 4);
          const float4 p4 = *(const float4*)(P4 + j4 * 4);
          const float4 p5 = *(const float4*)(P5 + j4 * 4);
          const float4 p6 = *(const float4*)(P6 + j4 * 4);
          const float4 p7 = *(const float4*)(P7 + j4 * 4);
          a0 += w4.x * p0.x + w4.y * p0.y + w4.z * p0.z + w4.w * p0.w;
          a1 += w4.x * p1.x + w4.y * p1.y + w4.z * p1.z + w4.w * p1.w;
          a2 += w4.x * p2.x + w4.y * p2.y + w4.z * p2.z + w4.w * p2.w;
          a3 += w4.x * p3.x + w4.y * p3.y + w4.z * p3.z + w4.w * p3.w;
          a4 += w4.x * p4.x + w4.y * p4.y + w4.z * p4.z + w4.w * p4.w;
          a5 += w4.x * p5.x + w4.y * p5.y + w4.z * p5.z + w4.w * p5.w;
          a6 += w4.x * p6.x + w4.y * p6.y + w4.z * p6.z + w4.w * p6.w;
          a7 += w4.x * p7.x + w4.y * p7.y + w4.z * p7.z + w4.w * p7.w;
        }
      }
    }

    red[h][lane][0] = make_float4(a0, a1, a2, a3);
    red[h][lane][1] = make_float4(a4, a5, a6, a7);
    __syncthreads();

    if (doW || doD) {
      const float4 r0 = red[0][lane][half], r1 = red[1][lane][half];
      const float4 r2 = red[2][lane][half], r3 = red[3][lane][half];
      const float s0 = (r0.x + r1.x) + (r2.x + r3.x);
      const float s1 = (r0.y + r1.y) + (r2.y + r3.y);
      const float s2 = (r0.z + r1.z) + (r2.z + r3.z);
      const float s3 = (r0.w + r1.w) + (r2.w + r3.w);
      const float4 cl = *(const float4*)(colLSE + ic);
      const float e0 = __expf(iv.x - cl.x), e1 = __expf(iv.y - cl.y);
      const float e2 = __expf(iv.z - cl.z), e3 = __expf(iv.w - cl.w);

      if (doW) {
        float w0 = s0 * e0, w1 = s1 * e1, w2 = s2 * e2, w3 = s3 * e3;
        float c0 = w0, c1 = w1, c2 = w2, c3 = w3;
        #pragma unroll
        for (int o = 32; o; o >>= 1) {
          c0 += __shfl_xor(c0, o);
          c1 += __shfl_xor(c1, o);
          c2 += __shfl_xor(c2, o);
          c3 += __shfl_xor(c3, o);
        }
        float4 wo;
        wo.x = w0 / c0; wo.y = w1 / c1; wo.z = w2 / c2; wo.w = w3 / c3;
        ((float4*)(c ? wD : wC))[(size_t)g4 * 64 + lane] = wo;
      } else {
        const float dp = s0 * e0 + s1 * e1 + s2 * e2 + s3 * e3;
        dotpart[((size_t)td * 128 + g4) * BB + lane] = dp;
      }
    }

    gbar(cntC, genC, NBLK / 2);
  }

  // ---- Phase D: final reduction (needs both chains' dotpart) ------------
  gbar(cntF, genF, NBLK);
  #pragma unroll
  for (int tt = 0; tt < 2; ++tt) {
    const int t = blk + tt * 128;
    float sum = 0.f;
    for (int s = h; s < 128; s += 4)
      sum += dotpart[((size_t)t * 128 + s) * BB + lane];
    red[h][lane][0].x = sum;
    __syncthreads();
    if (h == 0) {
      float tot = (red[0][lane][0].x + red[1][lane][0].x) +
                  (red[2][lane][0].x + red[3][lane][0].x);
      float v = __logf(tot) * masks[lane * TT + t];
      #pragma unroll
      for (int o = 32; o; o >>= 1) v += __shfl_xor(v, o);
      if (lane == 0) atomicAdd(out, v);
    }
    __syncthreads();
  }
}

extern "C" void kernel_launch(void* const* d_in, const int* in_sizes, int n_in,
                              void* d_out, int out_size, void* d_ws, size_t ws_size,
                              hipStream_t stream) {
  const int* sent = (const int*)d_in[0];      // [64][256] int32
  const float* masks = (const float*)d_in[1]; // [64][256]
  const float* iw = (const float*)d_in[2];    // [32000][512]
  const float* trans = (const float*)d_in[3]; // [512][512]
  const float* begin = (const float*)d_in[4]; // [512]
  float* out = (float*)d_out;
  float* ws = (float*)d_ws;

  // workspace carve (floats)
  float* P = ws;                          // 262144
  float* colLSE = P + 262144;             // 512
  float* psum = colLSE + 512;             // 256*512 = 131072
  float* sb = psum + 131072;              // 512
  float* q0vec = sb + 512;                // 512
  float* wring = q0vec + 512;             // 4 * 512*64 = 131072
  float* dotpart = wring + 4 * (BB * SS); // 256*128*64 = 2097152
  unsigned* bar = (unsigned*)(dotpart + 2097152);  // 256 slots
  // total ~2.62M floats ~10.5 MB

  k_init<<<1, 256, 0, stream>>>(out, bar);

  void* args[] = {(void*)&sent, (void*)&masks, (void*)&iw, (void*)&trans,
                  (void*)&begin, (void*)&P, (void*)&colLSE, (void*)&psum,
                  (void*)&sb, (void*)&q0vec, (void*)&wring, (void*)&dotpart,
                  (void*)&out, (void*)&bar};
  hipLaunchCooperativeKernel((void*)k_hmm, dim3(NBLK), dim3(256), args, 0, stream);
}

// Round 7
// 1695.064 us; speedup vs baseline: 2.8542x; 1.5496x over previous
//
#include <hip/hip_runtime.h>
#include <math.h>

#define SS 512
#define BB 64
#define TT 256
#define NBLK 128
#define AG __HIP_MEMORY_SCOPE_AGENT

typedef float f4 __attribute__((ext_vector_type(4)));

// All cross-block traffic uses relaxed agent-scope atomics: they compile to
// global_load/store with sc0 sc1 (bypass L1/L2, coherent at LLC) and emit NO
// cache-maintenance (no wbl2/inv tag-walks — R5's 19us/step killer).
__device__ __forceinline__ void st4(float* p, float v) {
  __hip_atomic_store(p, v, __ATOMIC_RELAXED, AG);
}
__device__ __forceinline__ float ld4(const float* p) {
  return __hip_atomic_load((float*)p, __ATOMIC_RELAXED, AG);
}
__device__ __forceinline__ unsigned long long ld8(const unsigned long long* p) {
  return __hip_atomic_load((unsigned long long*)p, __ATOMIC_RELAXED, AG);
}

__device__ __forceinline__ float wredsum(float v) {
#pragma unroll
  for (int o = 32; o; o >>= 1) v += __shfl_xor(v, o);
  return v;
}

// Tree barrier on LLC: 8 counter cells (128B apart, monotonic across steps),
// master (idx==0) polls cells then bumps gen; others spin on gen. No fences.
__device__ __forceinline__ void gbar(unsigned* cells, unsigned* gen,
                                     int idx, unsigned step, unsigned perCell) {
  __syncthreads();
  if (threadIdx.x == 0) {
    __hip_atomic_fetch_add(&cells[(idx & 7) * 32], 1u, __ATOMIC_RELAXED, AG);
    const unsigned tgt = step + 1u;
    if (idx == 0) {
      const unsigned ctgt = tgt * perCell;
      for (;;) {
        unsigned v0 = __hip_atomic_load(&cells[0 * 32], __ATOMIC_RELAXED, AG);
        unsigned v1 = __hip_atomic_load(&cells[1 * 32], __ATOMIC_RELAXED, AG);
        unsigned v2 = __hip_atomic_load(&cells[2 * 32], __ATOMIC_RELAXED, AG);
        unsigned v3 = __hip_atomic_load(&cells[3 * 32], __ATOMIC_RELAXED, AG);
        unsigned v4 = __hip_atomic_load(&cells[4 * 32], __ATOMIC_RELAXED, AG);
        unsigned v5 = __hip_atomic_load(&cells[5 * 32], __ATOMIC_RELAXED, AG);
        unsigned v6 = __hip_atomic_load(&cells[6 * 32], __ATOMIC_RELAXED, AG);
        unsigned v7 = __hip_atomic_load(&cells[7 * 32], __ATOMIC_RELAXED, AG);
        if (v0 >= ctgt && v1 >= ctgt && v2 >= ctgt && v3 >= ctgt &&
            v4 >= ctgt && v5 >= ctgt && v6 >= ctgt && v7 >= ctgt)
          break;
        __builtin_amdgcn_s_sleep(1);
      }
      __hip_atomic_store(gen, tgt, __ATOMIC_RELAXED, AG);
    } else {
      while (__hip_atomic_load(gen, __ATOMIC_RELAXED, AG) < tgt)
        __builtin_amdgcn_s_sleep(1);
    }
  }
  __syncthreads();
}

__global__ void k_init(float* __restrict__ out, unsigned* __restrict__ bar) {
  if (threadIdx.x == 0) out[0] = 0.f;
  bar[threadIdx.x] = 0u;  // 1024 slots
}

// w-load helpers: 16 u64 per group, fully unrolled -> registers (SROA).
__device__ __forceinline__ void ldgrp(const unsigned long long* w8, int g,
                                      unsigned long long* buf) {
#pragma unroll
  for (int k = 0; k < 16; ++k) buf[k] = ld8(w8 + (size_t)g * 1024 + k * 64);
}
__device__ __forceinline__ void fmagrp(const unsigned long long* buf, int g,
                                       const float* prow, float* acc) {
#pragma unroll
  for (int k = 0; k < 16; ++k) {
    const int j2 = g * 16 + k;
    const float w0 = __uint_as_float((unsigned)(buf[k] & 0xffffffffull));
    const float w1 = __uint_as_float((unsigned)(buf[k] >> 32));
#pragma unroll
    for (int i = 0; i < 8; ++i) {
      const float2 p = *(const float2*)(prow + i * SS + 2 * j2);  // uniform
      acc[i] = fmaf(w0, p.x, acc[i]);
      acc[i] = fmaf(w1, p.y, acc[i]);
    }
  }
}

// Persistent kernel, 128 blocks x 256 thr. chain = blk&1, grp = blk>>1,
// block owns 8 columns c0 = grp*8. Wave h = K-quarter; lane = batch b.
// w slab layout (per chain, 2 slots): float idx (j2*64 + b)*2 + (j&1),
// i.e. u64 (j2*64+b) holds states {2j2, 2j2+1} of batch b.
__global__ __launch_bounds__(256) void k_hmm(
    const int* __restrict__ sent, const float* __restrict__ masks,
    const float* __restrict__ iw, const float* __restrict__ trans,
    const float* __restrict__ begin,
    float* __restrict__ Pown, float* __restrict__ psum,
    float* __restrict__ wr, float* __restrict__ part,
    float* __restrict__ out, unsigned* __restrict__ bar) {
  const int blk = blockIdx.x;
  const int tid = threadIdx.x;
  const int lane = tid & 63;
  const int h = __builtin_amdgcn_readfirstlane(tid >> 6);
  const int chain = blk & 1;
  const int grp = blk >> 1;
  const int c0 = grp * 8;

  __shared__ float red[4][8][64];
  __shared__ float dpred[4][64];
  __shared__ float sb_l[512];
  __shared__ float redq[4][8];
  __shared__ float colLSE_l[8];

  unsigned* cellsC = bar + chain * 288;
  unsigned* genC = bar + chain * 288 + 256;
  unsigned* cellsS = bar + 576;
  unsigned* genS = bar + 832;

  float* myP = Pown + (size_t)blk * 8 * SS;
  float* ringc = wr + (size_t)chain * 2 * SS * BB;
  float* partc = part + (size_t)chain * 128 * 64 * 64;

  // ---- setup: psum partials (all blocks), own P rows, sb, slab-1 fill ----
  {
    const int cg4 = tid & 127;
    const int rh = tid >> 7;
    const int r0 = blk * 250;
    const f4* iw4 = (const f4*)iw;
    f4 s = {};
    for (int r = rh; r < 250; r += 2) {
      f4 x = iw4[(size_t)(r0 + r) * 128 + cg4];
      s.x += __expf(x.x); s.y += __expf(x.y);
      s.z += __expf(x.z); s.w += __expf(x.w);
    }
    float* pdst = psum + (size_t)(blk * 2 + rh) * SS + cg4 * 4;
    st4(pdst + 0, s.x); st4(pdst + 1, s.y);
    st4(pdst + 2, s.z); st4(pdst + 3, s.w);
  }
  // own P rows: wave h does rows {h, h+4} of trans[c0..c0+8)
#pragma unroll
  for (int rr = 0; rr < 2; ++rr) {
    const int i = h + rr * 4;  // local col
    const float* rp = trans + (size_t)(c0 + i) * SS;
    float xs[8];
    float m = -1e30f;
#pragma unroll
    for (int cc = 0; cc < 8; ++cc) {
      xs[cc] = rp[cc * 64 + lane];
      m = fmaxf(m, xs[cc]);
    }
#pragma unroll
    for (int o = 32; o; o >>= 1) m = fmaxf(m, __shfl_xor(m, o));
    float sm = 0.f;
#pragma unroll
    for (int cc = 0; cc < 8; ++cc) sm += __expf(xs[cc] - m);
#pragma unroll
    for (int o = 32; o; o >>= 1) sm += __shfl_xor(sm, o);
    const float lse = m + __logf(sm);
#pragma unroll
    for (int cc = 0; cc < 8; ++cc)
      myP[(size_t)i * SS + cc * 64 + lane] = __expf(xs[cc] - lse);
  }
  // sb = softmax(begin) into LDS (wave 0)
  if (h == 0) {
    float xs[8];
    float m = -1e30f;
#pragma unroll
    for (int cc = 0; cc < 8; ++cc) {
      xs[cc] = begin[cc * 64 + lane];
      m = fmaxf(m, xs[cc]);
    }
#pragma unroll
    for (int o = 32; o; o >>= 1) m = fmaxf(m, __shfl_xor(m, o));
    float sm = 0.f;
#pragma unroll
    for (int cc = 0; cc < 8; ++cc) sm += __expf(xs[cc] - m);
#pragma unroll
    for (int o = 32; o; o >>= 1) sm += __shfl_xor(sm, o);
    const float inv = 1.f / sm;
#pragma unroll
    for (int cc = 0; cc < 8; ++cc)
      sb_l[cc * 64 + lane] = __expf(xs[cc] - m) * inv;
  }
  __syncthreads();
  // pre-fill own chain's slab 1 with w = sb (makes step-0 GEMM produce q0)
  if (h == 0) {
    float* slab1 = ringc + SS * BB;
#pragma unroll
    for (int il = 0; il < 8; ++il) {
      const int j = c0 + il;
      st4(slab1 + ((size_t)(j >> 1) * 64 + lane) * 2 + (j & 1), sb_l[j]);
    }
  }
  gbar(cellsS, genS, blk, 0, 16);

  // ---- colLSE for own 8 columns from psum (256 partial rows) -------------
  {
    const float* prow = psum + (size_t)tid * SS + c0;  // row = tid
    float s[8];
#pragma unroll
    for (int i = 0; i < 8; ++i) s[i] = ld4(prow + i);
#pragma unroll
    for (int i = 0; i < 8; ++i) {
      const float ws = wredsum(s[i]);
      if (lane == 0) redq[h][i] = ws;
    }
    __syncthreads();
    if (tid < 8)
      colLSE_l[tid] = __logf(redq[0][tid] + redq[1][tid] + redq[2][tid] +
                             redq[3][tid]);
    __syncthreads();
  }

  // ---- supersteps --------------------------------------------------------
  const int smax = 129 - chain;
  const unsigned long long* w8base;
  const float* prow = myP + h * 128;  // + i*SS + 2*j2 inside fmagrp

  for (int s = 0; s < smax; ++s) {
    const float* wsrc = ringc + (size_t)((s + 1) & 1) * SS * BB;
    float* wdst = ringc + (size_t)(s & 1) * SS * BB;
    const int tw = 2 * s + chain;
    const int td = tw - 1;
    const bool doW = (tw <= 254);
    const bool doD = (td >= 0);
    const int ila = h, ilb = h + 4;

    // prefetch scattered iw gathers (overlap GEMM)
    float ivWa = 0.f, ivWb = 0.f, ivDa = 0.f, ivDb = 0.f;
    if (doW) {
      const int row = sent[lane * TT + tw];
      ivWa = iw[(size_t)row * SS + c0 + ila];
      ivWb = iw[(size_t)row * SS + c0 + ilb];
    }
    if (doD) {
      const int row = sent[lane * TT + td];
      ivDa = iw[(size_t)row * SS + c0 + ila];
      ivDb = iw[(size_t)row * SS + c0 + ilb];
    }

    // GEMM: acc[i] = sum_{j in quarter} w[b][j] * P[c0+i][j]
    float acc[8] = {0.f, 0.f, 0.f, 0.f, 0.f, 0.f, 0.f, 0.f};
    w8base = (const unsigned long long*)wsrc + (size_t)h * 64 * 64;
    {
      unsigned long long wa[16], wb[16];
      ldgrp(w8base, 0, wa);
      ldgrp(w8base, 1, wb);
      fmagrp(wa, 0, prow, acc);
      ldgrp(w8base, 2, wa);
      fmagrp(wb, 1, prow, acc);
      ldgrp(w8base, 3, wb);
      fmagrp(wa, 2, prow, acc);
      fmagrp(wb, 3, prow, acc);
    }
#pragma unroll
    for (int i = 0; i < 8; ++i) red[h][i][lane] = acc[i];
    __syncthreads();

    // tail: wave h handles cols {h, h+4}
    const float sa = red[0][ila][lane] + red[1][ila][lane] +
                     red[2][ila][lane] + red[3][ila][lane];
    const float sbv = red[0][ilb][lane] + red[1][ilb][lane] +
                      red[2][ilb][lane] + red[3][ilb][lane];
    const float cla = colLSE_l[ila], clb = colLSE_l[ilb];

    if (doW) {
      float wa_ = sa * __expf(ivWa - cla);
      float wb_ = sbv * __expf(ivWb - clb);
      const float csa = wredsum(wa_);
      const float csb = wredsum(wb_);
      const int ja = c0 + ila, jb = c0 + ilb;
      st4(wdst + ((size_t)(ja >> 1) * 64 + lane) * 2 + (ja & 1), wa_ / csa);
      st4(wdst + ((size_t)(jb >> 1) * 64 + lane) * 2 + (jb & 1), wb_ / csb);
    }
    if (doD) {
      dpred[h][lane] = sa * __expf(ivDa - cla) + sbv * __expf(ivDb - clb);
    }
    __syncthreads();
    if (doD && h == 0) {
      const float tot = dpred[0][lane] + dpred[1][lane] + dpred[2][lane] +
                        dpred[3][lane];
      const int idx = chain ? s : (s - 1);
      st4(partc + ((size_t)idx * 64 + grp) * 64 + lane, tot);
    }
    gbar(cellsC, genC, grp, (unsigned)s, 8);
  }

  // ---- final: own chain's tds (2 per block) ------------------------------
#pragma unroll
  for (int rr = 0; rr < 2; ++rr) {
    const int idx = grp * 2 + rr;
    const int td = 2 * idx + (chain ? 0 : 1);
    float psv = 0.f;
    for (int g = h * 16; g < h * 16 + 16; ++g)
      psv += ld4(partc + ((size_t)idx * 64 + g) * 64 + lane);
    dpred[h][lane] = psv;
    __syncthreads();
    if (h == 0) {
      const float tot = dpred[0][lane] + dpred[1][lane] + dpred[2][lane] +
                        dpred[3][lane];
      float v = __logf(tot) * masks[lane * TT + td];
      v = wredsum(v);
      if (lane == 0) atomicAdd(out, v);
    }
    __syncthreads();
  }
}

extern "C" void kernel_launch(void* const* d_in, const int* in_sizes, int n_in,
                              void* d_out, int out_size, void* d_ws, size_t ws_size,
                              hipStream_t stream) {
  const int* sent = (const int*)d_in[0];      // [64][256] int32
  const float* masks = (const float*)d_in[1]; // [64][256]
  const float* iw = (const float*)d_in[2];    // [32000][512]
  const float* trans = (const float*)d_in[3]; // [512][512]
  const float* begin = (const float*)d_in[4]; // [512]
  float* out = (float*)d_out;
  float* ws = (float*)d_ws;

  // workspace carve (floats)
  float* Pown = ws;                 // 128*8*512 = 524288
  float* psum = Pown + 524288;      // 256*512 = 131072
  float* wr = psum + 131072;        // 2 chains * 2 slots * 512*64 = 131072
  float* part = wr + 131072;        // 2*128*64*64 = 1048576
  unsigned* bar = (unsigned*)(part + 1048576);  // 1024 u32
  // total ~1.84M floats (~7.4 MB)

  k_init<<<1, 1024, 0, stream>>>(out, bar);

  void* args[] = {(void*)&sent, (void*)&masks, (void*)&iw, (void*)&trans,
                  (void*)&begin, (void*)&Pown, (void*)&psum, (void*)&wr,
                  (void*)&part, (void*)&out, (void*)&bar};
  hipLaunchCooperativeKernel((void*)k_hmm, dim3(NBLK), dim3(256), args, 0,
                             stream);
}